// Round 10
// baseline (367.598 us; speedup 1.0000x reference)
//
#include <hip/hip_runtime.h>

#define E_DIM 1024
#define S_LEN 1024
#define H_NUM 16
#define HD_DIM 64
#define B_NUM 8
#define DFF_DIM 4096
#define NROWS 8192   // B*S
#define QKV_LD 3072  // fused qkv row stride

typedef unsigned short u16;
typedef unsigned u32;
typedef short bf16v8 __attribute__((ext_vector_type(8)));
typedef float f32x4 __attribute__((ext_vector_type(4)));
typedef float f32x16 __attribute__((ext_vector_type(16)));

// softmax scale folded into Q projection: 1/sqrt(64) * log2(e)
#define QK_SCALE 0.18033688011112042f

__device__ __forceinline__ u16 f2b(float f) {
  union { float f; unsigned u; } x; x.f = f;
  return (u16)((x.u + 0x7fffu + ((x.u >> 16) & 1u)) >> 16);
}

__device__ __forceinline__ float b2f(u16 v) {
  union { unsigned u; float f; } x; x.u = ((unsigned)v) << 16; return x.f;
}

__device__ __forceinline__ float max3f(float a, float b, float c) {
  return fmaxf(fmaxf(a, b), c);  // clang fuses to v_max3_f32
}

__device__ __forceinline__ void gload16(const void* g, void* l) {
  __builtin_amdgcn_global_load_lds((const __attribute__((address_space(1))) void*)g,
                                   (__attribute__((address_space(3))) void*)l, 16, 0, 0);
}

// ================= 8-phase-style GEMM, BM=BN=256, BK=64, 512 thr, 8 waves =================
// R7-verified schedule (full-tile prefetch, counted vmcnt(8)).
// R10: operand-swapped MFMA — mfma(b, a, acc) gives C^T fragment layout where
// reg index i = 4 consecutive C-columns at a lane-fixed row, so the C-write is
// 32x ushort4 (8B) stores/thread instead of 128x 2B scalar stores.
// MODE 0: bf16 out, cols [1024,2048) scaled by QK_SCALE (fused QKV).
// MODE 1: bf16 partial out (split-K: kh ? C1 : C0), no bias.        (Wo)
// MODE 2: bf16 out + bias + relu.                                    (FFN1)
// MODE 3: bf16 partial out + bias only on kh==0.                     (FFN2)
template<int MODE>
__global__ __launch_bounds__(512, 2) void gemm8(
    const u16* __restrict__ A, const u16* __restrict__ Bt,
    void* __restrict__ C0, void* __restrict__ C1, const float* __restrict__ bias,
    int N, int KA, int nxt, int NT) {
  __shared__ u16 sA[2 * 16384];
  __shared__ u16 sB[2 * 16384];

  const int tid = threadIdx.x;
  const int lane = tid & 63;
  const int wid = tid >> 6;
  const int wm = wid >> 2, wn = wid & 3;
  const int l15 = lane & 15, l4 = lane >> 4;
  const int pk0 = l4 ^ (l15 & 7);

  const int gx = gridDim.x;
  const int lin = blockIdx.y * gx + blockIdx.x;
  const int chunk = (gx * gridDim.y) >> 3;
  const int swz = (lin & 7) * chunk + (lin >> 3);
  const int bym = swz / gx, bxm = swz % gx;
  const int kh = (bxm >= nxt) ? 1 : 0;
  const int bm = bym * 256;
  const int bn = (bxm - kh * nxt) * 256;
  const int k0 = kh * NT * 64;

  const int srow = tid >> 3;
  const int gch = ((tid & 7) ^ (srow & 7)) * 8;
  const u16* Ag[4];
  const u16* Bg[4];
#pragma unroll
  for (int i = 0; i < 4; ++i) {
    Ag[i] = A + k0 + (size_t)(bm + i * 64 + srow) * KA + gch;
    Bg[i] = Bt + k0 + (size_t)(bn + i * 64 + srow) * KA + gch;
  }
  const int t8 = tid * 8;

#define ST1(tile, li)                                                              \
  do {                                                                             \
    if ((li) < 4) gload16(Ag[li] + (tile) * 64, sA + ((tile)&1) * 16384 + (li)*4096 + t8); \
    else gload16(Bg[(li)-4] + (tile) * 64, sB + ((tile)&1) * 16384 + ((li)-4) * 4096 + t8); \
  } while (0)
#define STG8(tile)                                         \
  if ((tile) < NT) {                                       \
    _Pragma("unroll") for (int li = 0; li < 8; ++li) ST1(tile, li); \
  }

  bf16v8 a[4][2], b[4][2];
  f32x4 acc[4][8];  // [nn][mp] — C^T fragments (operand-swapped MFMA)
#pragma unroll
  for (int n = 0; n < 4; ++n)
#pragma unroll
    for (int m = 0; m < 8; ++m) acc[n][m] = (f32x4){0.f, 0.f, 0.f, 0.f};

#define LDA(mh, buf)                                                        \
  {                                                                         \
    _Pragma("unroll") for (int mp = 0; mp < 4; ++mp) {                      \
      const u16* rp = (buf) + (size_t)(wm * 128 + (mh)*64 + mp * 16 + l15) * 64; \
      a[mp][0] = *(const bf16v8*)(rp + pk0 * 8);                            \
      a[mp][1] = *(const bf16v8*)(rp + (pk0 ^ 4) * 8);                      \
    }                                                                       \
  }
#define LDB(n0, buf)                                                        \
  {                                                                         \
    _Pragma("unroll") for (int nn = (n0); nn < (n0) + 2; ++nn) {            \
      const u16* rp = (buf) + (size_t)(wn * 64 + nn * 16 + l15) * 64;       \
      b[nn][0] = *(const bf16v8*)(rp + pk0 * 8);                            \
      b[nn][1] = *(const bf16v8*)(rp + (pk0 ^ 4) * 8);                      \
    }                                                                       \
  }
#define MMPH(mh, n0)                                                                      \
  {                                                                                       \
    __builtin_amdgcn_s_setprio(1);                                                        \
    _Pragma("unroll") for (int mp = 0; mp < 4; ++mp) {                                    \
      _Pragma("unroll") for (int nn = (n0); nn < (n0) + 2; ++nn) {                        \
        acc[nn][(mh)*4 + mp] = __builtin_amdgcn_mfma_f32_16x16x32_bf16(                   \
            b[nn][0], a[mp][0], acc[nn][(mh)*4 + mp], 0, 0, 0);                           \
        acc[nn][(mh)*4 + mp] = __builtin_amdgcn_mfma_f32_16x16x32_bf16(                   \
            b[nn][1], a[mp][1], acc[nn][(mh)*4 + mp], 0, 0, 0);                           \
      }                                                                                   \
    }                                                                                     \
    __builtin_amdgcn_s_setprio(0);                                                        \
  }

  // ---- prologue: tiles 0 and 1 fully staged; validate tile 0; pre-read frags ----
  STG8(0);
  STG8(1);
  __builtin_amdgcn_sched_barrier(0);
  asm volatile("s_waitcnt vmcnt(8)" ::: "memory");
  __builtin_amdgcn_s_barrier();
  LDA(0, sA);
  LDB(0, sB);

  for (int t = 0; t < NT; ++t) {
    u16* sAc = sA + (t & 1) * 16384;
    u16* sBc = sB + (t & 1) * 16384;
    u16* sAn = sA + ((t + 1) & 1) * 16384;
    u16* sBn = sB + ((t + 1) & 1) * 16384;
    // ---- p0 ----
    MMPH(0, 0);
    LDB(2, sBc);
    __builtin_amdgcn_s_barrier();
    // ---- p1 ---- (tile t buffer fully consumed after this phase)
    MMPH(0, 2);
    LDA(1, sAc);
    __builtin_amdgcn_s_barrier();
    // ---- p2: issue ALL of tile t+2 into buffer[t&1]; validate tile t+1 ----
    STG8(t + 2);
    MMPH(1, 0);
    __builtin_amdgcn_sched_barrier(0);
    if (t + 2 < NT)      asm volatile("s_waitcnt vmcnt(8)" ::: "memory");
    else if (t + 1 < NT) asm volatile("s_waitcnt vmcnt(0)" ::: "memory");
    __builtin_amdgcn_s_barrier();
    // ---- p3 ----
    MMPH(1, 2);
    if (t + 1 < NT) {
      LDA(0, sAn);
      LDB(0, sBn);
    }
    __builtin_amdgcn_s_barrier();
  }

  // ---- epilogue: C^T frag layout -> row = ...+mp*16+l15, col = ...+nn*16+4*l4+i ----
  const int lrow0 = bm + wm * 128 + l15;
  const int lcol0 = bn + wn * 64 + l4 * 4;
  const float scl = (MODE == 0 && ((bn >> 10) == 1)) ? QK_SCALE : 1.f;
  u16* Cw = (u16*)(kh ? C1 : C0);
#pragma unroll
  for (int mp = 0; mp < 8; ++mp) {
    const int row = lrow0 + mp * 16;
#pragma unroll
    for (int nn = 0; nn < 4; ++nn) {
      const int col = lcol0 + nn * 16;
      float4 bv = {0.f, 0.f, 0.f, 0.f};
      if (MODE == 2 || (MODE == 3 && kh == 0)) bv = *(const float4*)(bias + col);
      float v0 = acc[nn][mp][0] + bv.x;
      float v1 = acc[nn][mp][1] + bv.y;
      float v2 = acc[nn][mp][2] + bv.z;
      float v3 = acc[nn][mp][3] + bv.w;
      if (MODE == 2) {
        v0 = fmaxf(v0, 0.f); v1 = fmaxf(v1, 0.f);
        v2 = fmaxf(v2, 0.f); v3 = fmaxf(v3, 0.f);
      }
      if (MODE == 0) { v0 *= scl; v1 *= scl; v2 *= scl; v3 *= scl; }
      ushort4 st;
      st.x = f2b(v0); st.y = f2b(v1); st.z = f2b(v2); st.w = f2b(v3);
      *(ushort4*)(Cw + (size_t)row * N + col) = st;
    }
  }
#undef ST1
#undef STG8
#undef LDA
#undef LDB
#undef MMPH
}

// ---------------- Flash attention: 8 waves x 32 q, 32x32 MFMA, swapped ops ----------------
// (unchanged from R9 — verified)
#define MKPF(dst, A0, B0, C0, D0)                                             \
  {                                                                           \
    u32 sa = (u32)__shfl_xor((int)(A0), 32), sb = (u32)__shfl_xor((int)(B0), 32); \
    u32 sc = (u32)__shfl_xor((int)(C0), 32), sd = (u32)__shfl_xor((int)(D0), 32); \
    union { u32 u[4]; bf16v8 v; } cc;                                         \
    cc.u[0] = hi ? sc : (A0); cc.u[1] = hi ? sd : (B0);                       \
    cc.u[2] = hi ? (C0) : sa; cc.u[3] = hi ? (D0) : sb;                       \
    dst = cc.v;                                                               \
  }

__device__ __forceinline__ void vt_write64(u16* sVtBuf, int4 wv, int vr, int s8) {
  int4 w2;
  w2.x = __shfl_xor(wv.x, 8); w2.y = __shfl_xor(wv.y, 8);
  w2.z = __shfl_xor(wv.z, 8); w2.w = __shfl_xor(wv.w, 8);
  const int t = vr >> 1;
  const int odd = vr & 1;
  const u16* own = (const u16*)&wv;
  const u16* par = (const u16*)&w2;
  char* dstbase = (char*)sVtBuf + (t >> 2) * 1024 + (t & 3) * 4;
#pragma unroll
  for (int k = 0; k < 4; k++) {
    const unsigned lo = odd ? (unsigned)par[4 + k] : (unsigned)own[k];
    const unsigned h2 = odd ? (unsigned)own[4 + k] : (unsigned)par[k];
    const int d = s8 * 8 + k + (odd ? 4 : 0);
    const int dsw = d ^ s8;  // s8 == d>>3
    *(unsigned*)(dstbase + dsw * 16) = lo | (h2 << 16);
  }
}

__global__ __launch_bounds__(512, 4) void attn_fa(
    const u16* __restrict__ qkv, u16* __restrict__ attn) {
  __shared__ u16 sK[2][64 * 64];
  __shared__ u16 sVt[2][64 * 64];

  const int tid = threadIdx.x, lane = tid & 63;
  const int l31 = lane & 31, hi = lane >> 5;
  const int w = ((blockIdx.x & 7) << 6) + (blockIdx.x >> 3);  // XCD swizzle (512 blocks)
  const int bh = w >> 2;
  const int b = bh >> 4, h = bh & 15;
  const int qrow0 = (w & 3) * 256 + (tid >> 6) * 32;
  const size_t rowb = (size_t)b * S_LEN * QKV_LD;
  const u16* kg = qkv + rowb + h * HD_DIM;
  const u16* qg = qkv + rowb + 1024 + h * HD_DIM;
  const u16* vg = qkv + rowb + 2048 + h * HD_DIM;
  const size_t obase = (size_t)b * (S_LEN * E_DIM) + (size_t)h * HD_DIM;

  bf16v8 qf[4];
#pragma unroll
  for (int ks = 0; ks < 4; ++ks)
    qf[ks] = *(const bf16v8*)(qg + (size_t)(qrow0 + l31) * QKV_LD + ks * 16 + hi * 8);

  const int kr = tid >> 3;
  const int s8 = tid & 7;
  const u16* kgsrc = kg + (size_t)kr * QKV_LD + ((s8 ^ (kr & 7)) * 8);
  const u16* vgsrc = vg + (size_t)kr * QKV_LD + s8 * 8;

  f32x16 accT[2];
#pragma unroll
  for (int i = 0; i < 16; ++i) { accT[0][i] = 0.f; accT[1][i] = 0.f; }
  float mrun = -1e30f, lrun = 0.f;

  gload16(kgsrc, sK[0] + tid * 8);
  {
    int4 v0 = *(const int4*)(vgsrc);
    vt_write64(sVt[0], v0, kr, s8);
  }
  __syncthreads();

  for (int t = 0; t < 16; ++t) {
    const int cur = t & 1;
    int4 vreg;
    if (t < 15) {
      gload16(kgsrc + (size_t)(t + 1) * 64 * QKV_LD, sK[cur ^ 1] + tid * 8);
      vreg = *(const int4*)(vgsrc + (size_t)(t + 1) * 64 * QKV_LD);
    }

    f32x16 T0, T1;
#pragma unroll
    for (int i = 0; i < 16; ++i) { T0[i] = 0.f; T1[i] = 0.f; }
#pragma unroll
    for (int ks = 0; ks < 4; ++ks) {
      const int ch = ((2 * ks + hi) ^ (l31 & 7)) * 8;
      const bf16v8 k0 = *(const bf16v8*)(sK[cur] + (size_t)l31 * 64 + ch);
      const bf16v8 k1 = *(const bf16v8*)(sK[cur] + (size_t)(32 + l31) * 64 + ch);
      T0 = __builtin_amdgcn_mfma_f32_32x32x16_bf16(k0, qf[ks], T0, 0, 0, 0);
      T1 = __builtin_amdgcn_mfma_f32_32x32x16_bf16(k1, qf[ks], T1, 0, 0, 0);
    }

    // ---- online softmax: max3 tree + single cross-half shfl ----
    float ma = fmaxf(T0[0], T0[1]);
#pragma unroll
    for (int r = 2; r < 16; r += 2) ma = max3f(ma, T0[r], T0[r + 1]);
    float mb = fmaxf(T1[0], T1[1]);
#pragma unroll
    for (int r = 2; r < 16; r += 2) mb = max3f(mb, T1[r], T1[r + 1]);
    float mx = fmaxf(ma, mb);
    mx = fmaxf(mx, __shfl_xor(mx, 32));
    const bool skip = __all(mx <= mrun + 8.f);
    const float mnew = skip ? mrun : fmaxf(mrun, mx);
    float rs = 0.f;
#pragma unroll
    for (int r = 0; r < 16; ++r) { T0[r] = exp2f(T0[r] - mnew); rs += T0[r]; }
#pragma unroll
    for (int r = 0; r < 16; ++r) { T1[r] = exp2f(T1[r] - mnew); rs += T1[r]; }
    // lrun stays lane-local (esc uniform across the lane pair); merged in epilogue
    if (skip) {
      lrun += rs;
    } else {
      const float esc = exp2f(mrun - mnew);
      mrun = mnew;
      lrun = lrun * esc + rs;
#pragma unroll
      for (int r = 0; r < 16; ++r) { accT[0][r] *= esc; accT[1][r] *= esc; }
    }

    u32 P0[8], P1[8];
#pragma unroll
    for (int wd = 0; wd < 8; ++wd) {
      asm("v_cvt_pk_bf16_f32 %0, %1, %2" : "=v"(P0[wd]) : "v"(T0[2 * wd]), "v"(T0[2 * wd + 1]));
      asm("v_cvt_pk_bf16_f32 %0, %1, %2" : "=v"(P1[wd]) : "v"(T1[2 * wd]), "v"(T1[2 * wd + 1]));
    }
    bf16v8 pf[4];
    MKPF(pf[0], P0[0], P0[1], P0[2], P0[3]);
    MKPF(pf[1], P0[4], P0[5], P0[6], P0[7]);
    MKPF(pf[2], P1[0], P1[1], P1[2], P1[3]);
    MKPF(pf[3], P1[4], P1[5], P1[6], P1[7]);

#pragma unroll
    for (int dblk = 0; dblk < 2; ++dblk) {
      const int dd = dblk * 32 + l31;
      const int drow = (dd ^ (dd >> 3)) * 8;
#pragma unroll
      for (int ks = 0; ks < 4; ++ks) {
        const bf16v8 va = *(const bf16v8*)(sVt[cur] + (2 * ks + hi) * 512 + drow);
        accT[dblk] = __builtin_amdgcn_mfma_f32_32x32x16_bf16(va, pf[ks], accT[dblk], 0, 0, 0);
      }
    }

    if (t < 15) vt_write64(sVt[cur ^ 1], vreg, kr, s8);
    __syncthreads();
  }

  // ---- epilogue: merge lane-local lrun across halves, normalize, store ----
  lrun += __shfl_xor(lrun, 32);
  const float linv = 1.f / lrun;
  u16* orow = attn + obase + (size_t)(qrow0 + l31) * E_DIM;
#pragma unroll
  for (int dblk = 0; dblk < 2; ++dblk)
#pragma unroll
    for (int a4 = 0; a4 < 4; ++a4) {
      ushort4 st;
      st.x = f2b(accT[dblk][4 * a4 + 0] * linv);
      st.y = f2b(accT[dblk][4 * a4 + 1] * linv);
      st.z = f2b(accT[dblk][4 * a4 + 2] * linv);
      st.w = f2b(accT[dblk][4 * a4 + 3] * linv);
      *(ushort4*)(orow + dblk * 32 + a4 * 8 + hi * 4) = st;
    }
}

// ---------------- LayerNorm over bf16 inputs (1 block = 1 row of 1024), ddof=1 ----
// MODE 0: y = 2*(a+b), bf16 out (ln1 over Wo split-K partials)
// MODE 1: y = a+b+c,  f32 out  (ln2 over x1 + FFN2 partials)
template<int MODE>
__global__ __launch_bounds__(256) void ln_b16(
    const u16* __restrict__ a, const u16* __restrict__ b, const u16* __restrict__ c,
    const float* __restrict__ scale, const float* __restrict__ bias,
    float* __restrict__ outf, u16* __restrict__ outb) {
  const int row = blockIdx.x;
  const int tid = threadIdx.x;
  const size_t off = (size_t)row * 1024 + tid * 4;
  ushort4 av = *(const ushort4*)(a + off);
  ushort4 bv = *(const ushort4*)(b + off);
  float4 v;
  v.x = b2f(av.x) + b2f(bv.x);
  v.y = b2f(av.y) + b2f(bv.y);
  v.z = b2f(av.z) + b2f(bv.z);
  v.w = b2f(av.w) + b2f(bv.w);
  if (MODE == 0) {
    v.x *= 2.f; v.y *= 2.f; v.z *= 2.f; v.w *= 2.f;
  } else {
    ushort4 cv = *(const ushort4*)(c + off);
    v.x += b2f(cv.x); v.y += b2f(cv.y); v.z += b2f(cv.z); v.w += b2f(cv.w);
  }
  float s = v.x + v.y + v.z + v.w;
  float q = v.x * v.x + v.y * v.y + v.z * v.z + v.w * v.w;
#pragma unroll
  for (int o = 1; o < 64; o <<= 1) { s += __shfl_xor(s, o); q += __shfl_xor(q, o); }
  __shared__ float red[8];
  const int wave = tid >> 6, lane = tid & 63;
  if (lane == 0) { red[wave] = s; red[4 + wave] = q; }
  __syncthreads();
  s = red[0] + red[1] + red[2] + red[3];
  q = red[4] + red[5] + red[6] + red[7];
  const float mean = s * (1.f / 1024.f);
  const float var = (q - 1024.f * mean * mean) * (1.f / 1023.f);
  const float rstd = rsqrtf(var + 1e-5f);
  const int cc = tid * 4;
  float4 sc = *(const float4*)(scale + cc);
  float4 bi = *(const float4*)(bias + cc);
  float4 o;
  o.x = sc.x * (v.x - mean) * rstd + bi.x;
  o.y = sc.y * (v.y - mean) * rstd + bi.y;
  o.z = sc.z * (v.z - mean) * rstd + bi.z;
  o.w = sc.w * (v.w - mean) * rstd + bi.w;
  if (MODE == 0) {
    ushort4 ob;
    ob.x = f2b(o.x); ob.y = f2b(o.y); ob.z = f2b(o.z); ob.w = f2b(o.w);
    *(ushort4*)(outb + off) = ob;
  } else {
    *(float4*)(outf + off) = o;
  }
}

// ---------------- fp32 -> bf16 cast (4 elems/thread) ----------------
__global__ __launch_bounds__(256) void cast_bf16_k(const float* __restrict__ in,
                                                   u16* __restrict__ out, int n4) {
  const int i = blockIdx.x * blockDim.x + threadIdx.x;
  if (i >= n4) return;
  float4 v = *(const float4*)(in + (size_t)i * 4);
  ushort4 o;
  o.x = f2b(v.x); o.y = f2b(v.y); o.z = f2b(v.z); o.w = f2b(v.w);
  *(ushort4*)(out + (size_t)i * 4) = o;
}

// ---------------- 1024x1024 fp32 transpose + bf16 cast ----------------
__global__ __launch_bounds__(256) void transpose_cast_k(const float* __restrict__ in,
                                                        u16* __restrict__ out) {
  __shared__ float tile[32][33];
  const int tx = threadIdx.x & 31, ty = threadIdx.x >> 5;
  const int bx = blockIdx.x * 32, by = blockIdx.y * 32;
#pragma unroll
  for (int j = 0; j < 4; j++)
    tile[ty + j * 8][tx] = in[(size_t)(by + ty + j * 8) * 1024 + bx + tx];
  __syncthreads();
#pragma unroll
  for (int j = 0; j < 4; j++)
    out[(size_t)(bx + ty + j * 8) * 1024 + by + tx] = f2b(tile[tx][ty + j * 8]);
}

extern "C" void kernel_launch(void* const* d_in, const int* in_sizes, int n_in,
                              void* d_out, int out_size, void* d_ws, size_t ws_size,
                              hipStream_t stream) {
  const float* x    = (const float*)d_in[0];
  const float* in_w = (const float*)d_in[1];
  const float* out_w = (const float*)d_in[2];
  const float* ln1s = (const float*)d_in[3];
  const float* ln1b = (const float*)d_in[4];
  const float* ln2s = (const float*)d_in[5];
  const float* ln2b = (const float*)d_in[6];
  const float* w1   = (const float*)d_in[7];
  const float* b1   = (const float*)d_in[8];
  const float* w2   = (const float*)d_in[9];
  const float* b2   = (const float*)d_in[10];
  float* outp = (float*)d_out;

  char* ws = (char*)d_ws;
  // arena (peak 176,160,768 B):
  u16*   xb    = (u16*)(ws + 0);            // 16.8M; dead after QKV gemm
  u16*   qkv   = (u16*)(ws + 16777216);     // 50.3M; dead after attn
  u16*   attnb = (u16*)(ws + 0);            // 16.8M over dead xb; dead after Wo
  u16*   wo0   = (u16*)(ws + 67108864);     // 16.8M bf16 partial; dead after ln1
  u16*   wo1   = (u16*)(ws + 83886080);     // 16.8M bf16 partial; dead after ln1
  u16*   x1b   = (u16*)(ws + 100663296);    // 16.8M; read by FFN1 and ln2
  u16*   Hb    = (u16*)(ws + 0);            // 67.1M over dead xb/qkv/attnb
  u16*   ffn0b = (u16*)(ws + 67108864);     // 16.8M over dead wo0
  u16*   ffn1b = (u16*)(ws + 83886080);     // 16.8M over dead wo1
  u16*   wkt   = (u16*)(ws + 150994944);    // [3072][1024] concat k,q,v transposed
  u16*   wot   = wkt + 3145728;
  u16*   w1b   = wot + 1048576;
  u16*   w2b   = w1b + 4194304;
  (void)ws_size; (void)in_sizes; (void)n_in; (void)out_size;

  // casts / transposes
  cast_bf16_k<<<8192, 256, 0, stream>>>(x, xb, 2097152);
  cast_bf16_k<<<4096, 256, 0, stream>>>(w1, w1b, 1048576);
  cast_bf16_k<<<4096, 256, 0, stream>>>(w2, w2b, 1048576);
  dim3 tg(32, 32);
  transpose_cast_k<<<tg, 256, 0, stream>>>(in_w + 0,       wkt);            // k
  transpose_cast_k<<<tg, 256, 0, stream>>>(in_w + 1048576, wkt + 1048576); // q
  transpose_cast_k<<<tg, 256, 0, stream>>>(in_w + 2097152, wkt + 2097152); // v
  transpose_cast_k<<<tg, 256, 0, stream>>>(out_w,          wot);

  // fused QKV projection: [8192][3072], q block scaled by QK_SCALE
  gemm8<0><<<dim3(12, 32), 512, 0, stream>>>(xb, wkt, qkv, nullptr, nullptr, 3072, 1024, 12, 16);

  // attention: 512 blocks x 512 threads (256 q rows per block)
  attn_fa<<<512, 512, 0, stream>>>(qkv, attnb);

  // output projection, split-K=2 -> two bf16 partials
  gemm8<1><<<dim3(8, 32), 512, 0, stream>>>(attnb, wot, wo0, wo1, nullptr, 1024, 1024, 4, 8);

  // ln1: x1 = LN(2*(wo0+wo1)) -> bf16
  ln_b16<0><<<8192, 256, 0, stream>>>(wo0, wo1, nullptr, ln1s, ln1b, nullptr, x1b);

  // FFN1: bf16 + bias + relu
  gemm8<2><<<dim3(16, 32), 512, 0, stream>>>(x1b, w1b, Hb, nullptr, b1, 4096, 1024, 16, 16);

  // FFN2: split-K=2, bf16 partials (bias on partial 0)
  gemm8<3><<<dim3(8, 32), 512, 0, stream>>>(Hb, w2b, ffn0b, ffn1b, b2, 1024, 4096, 4, 32);

  // ln2: out = LN(x1 + ffn0 + ffn1) -> f32
  ln_b16<1><<<8192, 256, 0, stream>>>(x1b, ffn0b, ffn1b, ln2s, ln2b, outp, nullptr);
}

// Round 12
// 355.064 us; speedup vs baseline: 1.0353x; 1.0353x over previous
//
#include <hip/hip_runtime.h>

#define E_DIM 1024
#define S_LEN 1024
#define H_NUM 16
#define HD_DIM 64
#define B_NUM 8
#define DFF_DIM 4096
#define NROWS 8192   // B*S
#define QKV_LD 3072  // fused qkv row stride

typedef unsigned short u16;
typedef unsigned u32;
typedef short bf16v8 __attribute__((ext_vector_type(8)));
typedef float f32x4 __attribute__((ext_vector_type(4)));
typedef float f32x16 __attribute__((ext_vector_type(16)));

// softmax scale folded into Q projection: 1/sqrt(64) * log2(e)
#define QK_SCALE 0.18033688011112042f

__device__ __forceinline__ u16 f2b(float f) {
  union { float f; unsigned u; } x; x.f = f;
  return (u16)((x.u + 0x7fffu + ((x.u >> 16) & 1u)) >> 16);
}

__device__ __forceinline__ float b2f(u16 v) {
  union { unsigned u; float f; } x; x.u = ((unsigned)v) << 16; return x.f;
}

__device__ __forceinline__ float max3f(float a, float b, float c) {
  return fmaxf(fmaxf(a, b), c);  // clang fuses to v_max3_f32
}

__device__ __forceinline__ void gload16(const void* g, void* l) {
  __builtin_amdgcn_global_load_lds((const __attribute__((address_space(1))) void*)g,
                                   (__attribute__((address_space(3))) void*)l, 16, 0, 0);
}

// ================= GEMM, BM=BN=256, BK=64, 512 thr, 8 waves =================
// R12: m201-style phase discipline — per phase {ds_read; barrier; lgkmcnt(0);
// setprio MFMA cluster; barrier}. Reads of tile t complete by end of p1;
// STG8(t+2) at p2 (after p1-end barrier -> no WAR race); vmcnt(8) counted wait.
// MODE 0: bf16 out, cols [1024,2048) scaled by QK_SCALE (fused QKV).
// MODE 1: bf16 partial out (split-K: kh ? C1 : C0), no bias.        (Wo)
// MODE 2: bf16 out + bias + relu.                                    (FFN1)
// MODE 3: bf16 partial out + bias only on kh==0.                     (FFN2)
template<int MODE>
__global__ __launch_bounds__(512, 2) void gemm8(
    const u16* __restrict__ A, const u16* __restrict__ Bt,
    void* __restrict__ C0, void* __restrict__ C1, const float* __restrict__ bias,
    int N, int KA, int nxt, int NT) {
  __shared__ u16 sA[2 * 16384];
  __shared__ u16 sB[2 * 16384];

  const int tid = threadIdx.x;
  const int lane = tid & 63;
  const int wid = tid >> 6;
  const int wm = wid >> 2, wn = wid & 3;
  const int l15 = lane & 15, l4 = lane >> 4;
  const int pk0 = l4 ^ (l15 & 7);

  const int gx = gridDim.x;
  const int lin = blockIdx.y * gx + blockIdx.x;
  const int chunk = (gx * gridDim.y) >> 3;
  const int swz = (lin & 7) * chunk + (lin >> 3);
  const int bym = swz / gx, bxm = swz % gx;
  const int kh = (bxm >= nxt) ? 1 : 0;
  const int bm = bym * 256;
  const int bn = (bxm - kh * nxt) * 256;
  const int k0 = kh * NT * 64;

  const int srow = tid >> 3;
  const int gch = ((tid & 7) ^ (srow & 7)) * 8;
  const u16* Ag[4];
  const u16* Bg[4];
#pragma unroll
  for (int i = 0; i < 4; ++i) {
    Ag[i] = A + k0 + (size_t)(bm + i * 64 + srow) * KA + gch;
    Bg[i] = Bt + k0 + (size_t)(bn + i * 64 + srow) * KA + gch;
  }
  const int t8 = tid * 8;

#define ST1(tile, li)                                                              \
  do {                                                                             \
    if ((li) < 4) gload16(Ag[li] + (tile) * 64, sA + ((tile)&1) * 16384 + (li)*4096 + t8); \
    else gload16(Bg[(li)-4] + (tile) * 64, sB + ((tile)&1) * 16384 + ((li)-4) * 4096 + t8); \
  } while (0)
#define STG8(tile)                                         \
  if ((tile) < NT) {                                       \
    _Pragma("unroll") for (int li = 0; li < 8; ++li) ST1(tile, li); \
  }

  bf16v8 a[4][2], b[4][2];
  f32x4 acc[8][4];
#pragma unroll
  for (int m = 0; m < 8; ++m)
#pragma unroll
    for (int n = 0; n < 4; ++n) acc[m][n] = (f32x4){0.f, 0.f, 0.f, 0.f};

#define LDA(mh, buf)                                                        \
  {                                                                         \
    _Pragma("unroll") for (int mp = 0; mp < 4; ++mp) {                      \
      const u16* rp = (buf) + (size_t)(wm * 128 + (mh)*64 + mp * 16 + l15) * 64; \
      a[mp][0] = *(const bf16v8*)(rp + pk0 * 8);                            \
      a[mp][1] = *(const bf16v8*)(rp + (pk0 ^ 4) * 8);                      \
    }                                                                       \
  }
#define LDB(n0, buf)                                                        \
  {                                                                         \
    _Pragma("unroll") for (int nn = (n0); nn < (n0) + 2; ++nn) {            \
      const u16* rp = (buf) + (size_t)(wn * 64 + nn * 16 + l15) * 64;       \
      b[nn][0] = *(const bf16v8*)(rp + pk0 * 8);                            \
      b[nn][1] = *(const bf16v8*)(rp + (pk0 ^ 4) * 8);                      \
    }                                                                       \
  }
#define MMPH(mh, n0)                                                                      \
  {                                                                                       \
    __builtin_amdgcn_s_setprio(1);                                                        \
    _Pragma("unroll") for (int mp = 0; mp < 4; ++mp) {                                    \
      _Pragma("unroll") for (int nn = (n0); nn < (n0) + 2; ++nn) {                        \
        acc[(mh)*4 + mp][nn] = __builtin_amdgcn_mfma_f32_16x16x32_bf16(                   \
            a[mp][0], b[nn][0], acc[(mh)*4 + mp][nn], 0, 0, 0);                           \
        acc[(mh)*4 + mp][nn] = __builtin_amdgcn_mfma_f32_16x16x32_bf16(                   \
            a[mp][1], b[nn][1], acc[(mh)*4 + mp][nn], 0, 0, 0);                           \
      }                                                                                   \
    }                                                                                     \
    __builtin_amdgcn_s_setprio(0);                                                        \
  }
#define LGKM0()                                            \
  asm volatile("s_waitcnt lgkmcnt(0)" ::: "memory");       \
  __builtin_amdgcn_sched_barrier(0);

  // ---- prologue: tiles 0 and 1 fully staged; validate tile 0 ----
  STG8(0);
  STG8(1);
  __builtin_amdgcn_sched_barrier(0);
  asm volatile("s_waitcnt vmcnt(8)" ::: "memory");
  __builtin_amdgcn_s_barrier();

  for (int t = 0; t < NT; ++t) {
    u16* sAc = sA + (t & 1) * 16384;
    u16* sBc = sB + (t & 1) * 16384;
    // ---- p0: read A(mh0)+B(n01); aligned MFMA(mh0,n01) ----
    LDA(0, sAc);
    LDB(0, sBc);
    __builtin_amdgcn_s_barrier();
    LGKM0();
    MMPH(0, 0);
    __builtin_amdgcn_s_barrier();
    // ---- p1: read B(n23); MFMA(mh0,n23); then issue A(mh1) reads ----
    LDB(2, sBc);
    __builtin_amdgcn_s_barrier();
    LGKM0();
    MMPH(0, 2);
    LDA(1, sAc);   // issued before p1-end barrier; drained by p2's lgkmcnt(0)
    __builtin_amdgcn_s_barrier();
    // ---- p2: stage tile t+2 (buffer free: all tile-t reads issued); validate t+1 ----
    STG8(t + 2);
    __builtin_amdgcn_sched_barrier(0);
    if (t + 2 < NT)      asm volatile("s_waitcnt vmcnt(8)" ::: "memory");
    else if (t + 1 < NT) asm volatile("s_waitcnt vmcnt(0)" ::: "memory");
    __builtin_amdgcn_s_barrier();
    LGKM0();
    MMPH(1, 0);
    __builtin_amdgcn_s_barrier();
    // ---- p3 ----
    MMPH(1, 2);
    __builtin_amdgcn_s_barrier();
  }

  // ---- epilogue (R9-verified) ----
  const int lrow0 = bm + wm * 128 + l4 * 4;
  const int lcol0 = bn + wn * 64 + l15;
  const float scl = (MODE == 0 && ((bn >> 10) == 1)) ? QK_SCALE : 1.f;
  u16* Cw = (u16*)(kh ? C1 : C0);
#pragma unroll
  for (int m = 0; m < 8; ++m) {
#pragma unroll
    for (int n = 0; n < 4; ++n) {
      const int col = lcol0 + n * 16;
      float bv = 0.f;
      if (MODE == 2) bv = bias[col];
      if (MODE == 3) bv = kh ? 0.f : bias[col];
#pragma unroll
      for (int i = 0; i < 4; ++i) {
        const int row = lrow0 + m * 16 + i;
        float v = acc[m][n][i] + bv;
        if (MODE == 2) v = fmaxf(v, 0.f);
        if (MODE == 0) v *= scl;
        Cw[(size_t)row * N + col] = f2b(v);
      }
    }
  }
#undef ST1
#undef STG8
#undef LDA
#undef LDB
#undef MMPH
#undef LGKM0
}

// ---------------- Flash attention: 8 waves x 32 q, 32x32 MFMA, swapped ops ----------------
// R9-verified source, restored exactly (exp2f libm; permlane/builtin-exp2 dropped).
#define MKPF(dst, A0, B0, C0, D0)                                             \
  {                                                                           \
    u32 sa = (u32)__shfl_xor((int)(A0), 32), sb = (u32)__shfl_xor((int)(B0), 32); \
    u32 sc = (u32)__shfl_xor((int)(C0), 32), sd = (u32)__shfl_xor((int)(D0), 32); \
    union { u32 u[4]; bf16v8 v; } cc;                                         \
    cc.u[0] = hi ? sc : (A0); cc.u[1] = hi ? sd : (B0);                       \
    cc.u[2] = hi ? (C0) : sa; cc.u[3] = hi ? (D0) : sb;                       \
    dst = cc.v;                                                               \
  }

__device__ __forceinline__ void vt_write64(u16* sVtBuf, int4 wv, int vr, int s8) {
  int4 w2;
  w2.x = __shfl_xor(wv.x, 8); w2.y = __shfl_xor(wv.y, 8);
  w2.z = __shfl_xor(wv.z, 8); w2.w = __shfl_xor(wv.w, 8);
  const int t = vr >> 1;
  const int odd = vr & 1;
  const u16* own = (const u16*)&wv;
  const u16* par = (const u16*)&w2;
  char* dstbase = (char*)sVtBuf + (t >> 2) * 1024 + (t & 3) * 4;
#pragma unroll
  for (int k = 0; k < 4; k++) {
    const unsigned lo = odd ? (unsigned)par[4 + k] : (unsigned)own[k];
    const unsigned h2 = odd ? (unsigned)own[4 + k] : (unsigned)par[k];
    const int d = s8 * 8 + k + (odd ? 4 : 0);
    const int dsw = d ^ s8;  // s8 == d>>3
    *(unsigned*)(dstbase + dsw * 16) = lo | (h2 << 16);
  }
}

__global__ __launch_bounds__(512, 4) void attn_fa(
    const u16* __restrict__ qkv, u16* __restrict__ attn) {
  __shared__ u16 sK[2][64 * 64];
  __shared__ u16 sVt[2][64 * 64];

  const int tid = threadIdx.x, lane = tid & 63;
  const int l31 = lane & 31, hi = lane >> 5;
  const int w = ((blockIdx.x & 7) << 6) + (blockIdx.x >> 3);  // XCD swizzle (512 blocks)
  const int bh = w >> 2;
  const int b = bh >> 4, h = bh & 15;
  const int qrow0 = (w & 3) * 256 + (tid >> 6) * 32;
  const size_t rowb = (size_t)b * S_LEN * QKV_LD;
  const u16* kg = qkv + rowb + h * HD_DIM;
  const u16* qg = qkv + rowb + 1024 + h * HD_DIM;
  const u16* vg = qkv + rowb + 2048 + h * HD_DIM;
  const size_t obase = (size_t)b * (S_LEN * E_DIM) + (size_t)h * HD_DIM;

  bf16v8 qf[4];
#pragma unroll
  for (int ks = 0; ks < 4; ++ks)
    qf[ks] = *(const bf16v8*)(qg + (size_t)(qrow0 + l31) * QKV_LD + ks * 16 + hi * 8);

  const int kr = tid >> 3;
  const int s8 = tid & 7;
  const u16* kgsrc = kg + (size_t)kr * QKV_LD + ((s8 ^ (kr & 7)) * 8);
  const u16* vgsrc = vg + (size_t)kr * QKV_LD + s8 * 8;

  f32x16 accT[2];
#pragma unroll
  for (int i = 0; i < 16; ++i) { accT[0][i] = 0.f; accT[1][i] = 0.f; }
  float mrun = -1e30f, lrun = 0.f;

  gload16(kgsrc, sK[0] + tid * 8);
  {
    int4 v0 = *(const int4*)(vgsrc);
    vt_write64(sVt[0], v0, kr, s8);
  }
  __syncthreads();

  for (int t = 0; t < 16; ++t) {
    const int cur = t & 1;
    int4 vreg;
    if (t < 15) {
      gload16(kgsrc + (size_t)(t + 1) * 64 * QKV_LD, sK[cur ^ 1] + tid * 8);
      vreg = *(const int4*)(vgsrc + (size_t)(t + 1) * 64 * QKV_LD);
    }

    f32x16 T0, T1;
#pragma unroll
    for (int i = 0; i < 16; ++i) { T0[i] = 0.f; T1[i] = 0.f; }
#pragma unroll
    for (int ks = 0; ks < 4; ++ks) {
      const int ch = ((2 * ks + hi) ^ (l31 & 7)) * 8;
      const bf16v8 k0 = *(const bf16v8*)(sK[cur] + (size_t)l31 * 64 + ch);
      const bf16v8 k1 = *(const bf16v8*)(sK[cur] + (size_t)(32 + l31) * 64 + ch);
      T0 = __builtin_amdgcn_mfma_f32_32x32x16_bf16(k0, qf[ks], T0, 0, 0, 0);
      T1 = __builtin_amdgcn_mfma_f32_32x32x16_bf16(k1, qf[ks], T1, 0, 0, 0);
    }

    // ---- online softmax: max3 tree + single cross-half shfl ----
    float ma = fmaxf(T0[0], T0[1]);
#pragma unroll
    for (int r = 2; r < 16; r += 2) ma = max3f(ma, T0[r], T0[r + 1]);
    float mb = fmaxf(T1[0], T1[1]);
#pragma unroll
    for (int r = 2; r < 16; r += 2) mb = max3f(mb, T1[r], T1[r + 1]);
    float mx = fmaxf(ma, mb);
    mx = fmaxf(mx, __shfl_xor(mx, 32));
    const bool skip = __all(mx <= mrun + 8.f);
    const float mnew = skip ? mrun : fmaxf(mrun, mx);
    float rs = 0.f;
#pragma unroll
    for (int r = 0; r < 16; ++r) { T0[r] = exp2f(T0[r] - mnew); rs += T0[r]; }
#pragma unroll
    for (int r = 0; r < 16; ++r) { T1[r] = exp2f(T1[r] - mnew); rs += T1[r]; }
    // lrun stays lane-local (esc uniform across the lane pair); merged in epilogue
    if (skip) {
      lrun += rs;
    } else {
      const float esc = exp2f(mrun - mnew);
      mrun = mnew;
      lrun = lrun * esc + rs;
#pragma unroll
      for (int r = 0; r < 16; ++r) { accT[0][r] *= esc; accT[1][r] *= esc; }
    }

    u32 P0[8], P1[8];
#pragma unroll
    for (int wd = 0; wd < 8; ++wd) {
      asm("v_cvt_pk_bf16_f32 %0, %1, %2" : "=v"(P0[wd]) : "v"(T0[2 * wd]), "v"(T0[2 * wd + 1]));
      asm("v_cvt_pk_bf16_f32 %0, %1, %2" : "=v"(P1[wd]) : "v"(T1[2 * wd]), "v"(T1[2 * wd + 1]));
    }
    bf16v8 pf[4];
    MKPF(pf[0], P0[0], P0[1], P0[2], P0[3]);
    MKPF(pf[1], P0[4], P0[5], P0[6], P0[7]);
    MKPF(pf[2], P1[0], P1[1], P1[2], P1[3]);
    MKPF(pf[3], P1[4], P1[5], P1[6], P1[7]);

#pragma unroll
    for (int dblk = 0; dblk < 2; ++dblk) {
      const int dd = dblk * 32 + l31;
      const int drow = (dd ^ (dd >> 3)) * 8;
#pragma unroll
      for (int ks = 0; ks < 4; ++ks) {
        const bf16v8 va = *(const bf16v8*)(sVt[cur] + (2 * ks + hi) * 512 + drow);
        accT[dblk] = __builtin_amdgcn_mfma_f32_32x32x16_bf16(va, pf[ks], accT[dblk], 0, 0, 0);
      }
    }

    if (t < 15) vt_write64(sVt[cur ^ 1], vreg, kr, s8);
    __syncthreads();
  }

  // ---- epilogue: merge lane-local lrun across halves, normalize, store ----
  lrun += __shfl_xor(lrun, 32);
  const float linv = 1.f / lrun;
  u16* orow = attn + obase + (size_t)(qrow0 + l31) * E_DIM;
#pragma unroll
  for (int dblk = 0; dblk < 2; ++dblk)
#pragma unroll
    for (int a4 = 0; a4 < 4; ++a4) {
      ushort4 st;
      st.x = f2b(accT[dblk][4 * a4 + 0] * linv);
      st.y = f2b(accT[dblk][4 * a4 + 1] * linv);
      st.z = f2b(accT[dblk][4 * a4 + 2] * linv);
      st.w = f2b(accT[dblk][4 * a4 + 3] * linv);
      *(ushort4*)(orow + dblk * 32 + a4 * 8 + hi * 4) = st;
    }
}

// ---------------- LayerNorm over bf16 inputs (1 block = 1 row of 1024), ddof=1 ----
// MODE 0: y = 2*(a+b), bf16 out (ln1 over Wo split-K partials)
// MODE 1: y = a+b+c,  f32 out  (ln2 over x1 + FFN2 partials)
template<int MODE>
__global__ __launch_bounds__(256) void ln_b16(
    const u16* __restrict__ a, const u16* __restrict__ b, const u16* __restrict__ c,
    const float* __restrict__ scale, const float* __restrict__ bias,
    float* __restrict__ outf, u16* __restrict__ outb) {
  const int row = blockIdx.x;
  const int tid = threadIdx.x;
  const size_t off = (size_t)row * 1024 + tid * 4;
  ushort4 av = *(const ushort4*)(a + off);
  ushort4 bv = *(const ushort4*)(b + off);
  float4 v;
  v.x = b2f(av.x) + b2f(bv.x);
  v.y = b2f(av.y) + b2f(bv.y);
  v.z = b2f(av.z) + b2f(bv.z);
  v.w = b2f(av.w) + b2f(bv.w);
  if (MODE == 0) {
    v.x *= 2.f; v.y *= 2.f; v.z *= 2.f; v.w *= 2.f;
  } else {
    ushort4 cv = *(const ushort4*)(c + off);
    v.x += b2f(cv.x); v.y += b2f(cv.y); v.z += b2f(cv.z); v.w += b2f(cv.w);
  }
  float s = v.x + v.y + v.z + v.w;
  float q = v.x * v.x + v.y * v.y + v.z * v.z + v.w * v.w;
#pragma unroll
  for (int o = 1; o < 64; o <<= 1) { s += __shfl_xor(s, o); q += __shfl_xor(q, o); }
  __shared__ float red[8];
  const int wave = tid >> 6, lane = tid & 63;
  if (lane == 0) { red[wave] = s; red[4 + wave] = q; }
  __syncthreads();
  s = red[0] + red[1] + red[2] + red[3];
  q = red[4] + red[5] + red[6] + red[7];
  const float mean = s * (1.f / 1024.f);
  const float var = (q - 1024.f * mean * mean) * (1.f / 1023.f);
  const float rstd = rsqrtf(var + 1e-5f);
  const int cc = tid * 4;
  float4 sc = *(const float4*)(scale + cc);
  float4 bi = *(const float4*)(bias + cc);
  float4 o;
  o.x = sc.x * (v.x - mean) * rstd + bi.x;
  o.y = sc.y * (v.y - mean) * rstd + bi.y;
  o.z = sc.z * (v.z - mean) * rstd + bi.z;
  o.w = sc.w * (v.w - mean) * rstd + bi.w;
  if (MODE == 0) {
    ushort4 ob;
    ob.x = f2b(o.x); ob.y = f2b(o.y); ob.z = f2b(o.z); ob.w = f2b(o.w);
    *(ushort4*)(outb + off) = ob;
  } else {
    *(float4*)(outf + off) = o;
  }
}

// ---------------- fp32 -> bf16 cast (4 elems/thread) ----------------
__global__ __launch_bounds__(256) void cast_bf16_k(const float* __restrict__ in,
                                                   u16* __restrict__ out, int n4) {
  const int i = blockIdx.x * blockDim.x + threadIdx.x;
  if (i >= n4) return;
  float4 v = *(const float4*)(in + (size_t)i * 4);
  ushort4 o;
  o.x = f2b(v.x); o.y = f2b(v.y); o.z = f2b(v.z); o.w = f2b(v.w);
  *(ushort4*)(out + (size_t)i * 4) = o;
}

// ---------------- 1024x1024 fp32 transpose + bf16 cast ----------------
__global__ __launch_bounds__(256) void transpose_cast_k(const float* __restrict__ in,
                                                        u16* __restrict__ out) {
  __shared__ float tile[32][33];
  const int tx = threadIdx.x & 31, ty = threadIdx.x >> 5;
  const int bx = blockIdx.x * 32, by = blockIdx.y * 32;
#pragma unroll
  for (int j = 0; j < 4; j++)
    tile[ty + j * 8][tx] = in[(size_t)(by + ty + j * 8) * 1024 + bx + tx];
  __syncthreads();
#pragma unroll
  for (int j = 0; j < 4; j++)
    out[(size_t)(bx + ty + j * 8) * 1024 + by + tx] = f2b(tile[tx][ty + j * 8]);
}

extern "C" void kernel_launch(void* const* d_in, const int* in_sizes, int n_in,
                              void* d_out, int out_size, void* d_ws, size_t ws_size,
                              hipStream_t stream) {
  const float* x    = (const float*)d_in[0];
  const float* in_w = (const float*)d_in[1];
  const float* out_w = (const float*)d_in[2];
  const float* ln1s = (const float*)d_in[3];
  const float* ln1b = (const float*)d_in[4];
  const float* ln2s = (const float*)d_in[5];
  const float* ln2b = (const float*)d_in[6];
  const float* w1   = (const float*)d_in[7];
  const float* b1   = (const float*)d_in[8];
  const float* w2   = (const float*)d_in[9];
  const float* b2   = (const float*)d_in[10];
  float* outp = (float*)d_out;

  char* ws = (char*)d_ws;
  // arena (peak 176,160,768 B):
  u16*   xb    = (u16*)(ws + 0);            // 16.8M; dead after QKV gemm
  u16*   qkv   = (u16*)(ws + 16777216);     // 50.3M; dead after attn
  u16*   attnb = (u16*)(ws + 0);            // 16.8M over dead xb; dead after Wo
  u16*   wo0   = (u16*)(ws + 67108864);     // 16.8M bf16 partial; dead after ln1
  u16*   wo1   = (u16*)(ws + 83886080);     // 16.8M bf16 partial; dead after ln1
  u16*   x1b   = (u16*)(ws + 100663296);    // 16.8M; read by FFN1 and ln2
  u16*   Hb    = (u16*)(ws + 0);            // 67.1M over dead xb/qkv/attnb
  u16*   ffn0b = (u16*)(ws + 67108864);     // 16.8M over dead wo0
  u16*   ffn1b = (u16*)(ws + 83886080);     // 16.8M over dead wo1
  u16*   wkt   = (u16*)(ws + 150994944);    // [3072][1024] concat k,q,v transposed
  u16*   wot   = wkt + 3145728;
  u16*   w1b   = wot + 1048576;
  u16*   w2b   = w1b + 4194304;
  (void)ws_size; (void)in_sizes; (void)n_in; (void)out_size;

  // casts / transposes
  cast_bf16_k<<<8192, 256, 0, stream>>>(x, xb, 2097152);
  cast_bf16_k<<<4096, 256, 0, stream>>>(w1, w1b, 1048576);
  cast_bf16_k<<<4096, 256, 0, stream>>>(w2, w2b, 1048576);
  dim3 tg(32, 32);
  transpose_cast_k<<<tg, 256, 0, stream>>>(in_w + 0,       wkt);            // k
  transpose_cast_k<<<tg, 256, 0, stream>>>(in_w + 1048576, wkt + 1048576); // q
  transpose_cast_k<<<tg, 256, 0, stream>>>(in_w + 2097152, wkt + 2097152); // v
  transpose_cast_k<<<tg, 256, 0, stream>>>(out_w,          wot);

  // fused QKV projection: [8192][3072], q block scaled by QK_SCALE
  gemm8<0><<<dim3(12, 32), 512, 0, stream>>>(xb, wkt, qkv, nullptr, nullptr, 3072, 1024, 12, 16);

  // attention: 512 blocks x 512 threads (256 q rows per block)
  attn_fa<<<512, 512, 0, stream>>>(qkv, attnb);

  // output projection, split-K=2 -> two bf16 partials
  gemm8<1><<<dim3(8, 32), 512, 0, stream>>>(attnb, wot, wo0, wo1, nullptr, 1024, 1024, 4, 8);

  // ln1: x1 = LN(2*(wo0+wo1)) -> bf16
  ln_b16<0><<<8192, 256, 0, stream>>>(wo0, wo1, nullptr, ln1s, ln1b, nullptr, x1b);

  // FFN1: bf16 + bias + relu
  gemm8<2><<<dim3(16, 32), 512, 0, stream>>>(x1b, w1b, Hb, nullptr, b1, 4096, 1024, 16, 16);

  // FFN2: split-K=2, bf16 partials (bias on partial 0)
  gemm8<3><<<dim3(8, 32), 512, 0, stream>>>(Hb, w2b, ffn0b, ffn1b, b2, 1024, 4096, 4, 32);

  // ln2: out = LN(x1 + ffn0 + ffn1) -> f32
  ln_b16<1><<<8192, 256, 0, stream>>>(x1b, ffn0b, ffn1b, ln2s, ln2b, outp, nullptr);
}

// Round 13
// 343.119 us; speedup vs baseline: 1.0713x; 1.0348x over previous
//
#include <hip/hip_runtime.h>

#define E_DIM 1024
#define S_LEN 1024
#define H_NUM 16
#define HD_DIM 64
#define B_NUM 8
#define DFF_DIM 4096
#define NROWS 8192   // B*S
#define QKV_LD 3072  // fused qkv row stride

typedef unsigned short u16;
typedef unsigned u32;
typedef short bf16v8 __attribute__((ext_vector_type(8)));
typedef float f32x4 __attribute__((ext_vector_type(4)));
typedef float f32x16 __attribute__((ext_vector_type(16)));

// softmax scale folded into Q projection: 1/sqrt(64) * log2(e)
#define QK_SCALE 0.18033688011112042f

__device__ __forceinline__ u16 f2b(float f) {
  union { float f; unsigned u; } x; x.f = f;
  return (u16)((x.u + 0x7fffu + ((x.u >> 16) & 1u)) >> 16);
}

__device__ __forceinline__ float b2f(u16 v) {
  union { unsigned u; float f; } x; x.u = ((unsigned)v) << 16; return x.f;
}

__device__ __forceinline__ float max3f(float a, float b, float c) {
  return fmaxf(fmaxf(a, b), c);  // clang fuses to v_max3_f32
}

__device__ __forceinline__ void gload16(const void* g, void* l) {
  __builtin_amdgcn_global_load_lds((const __attribute__((address_space(1))) void*)g,
                                   (__attribute__((address_space(3))) void*)l, 16, 0, 0);
}

// ================= GEMM, BM=BN=256, BK=64, 512 thr, 8 waves =================
// R9-verified schedule (full-tile prefetch, counted vmcnt(8); R12 phase
// discipline REVERTED — regressed 75.8->80.5).
// R13: column-major tile order WITHIN each XCD stripe (B-panel fetched once
// per XCD instead of once per round; A-row set stays L2-warm).
// MODE 0: bf16 out, cols [1024,2048) scaled by QK_SCALE (fused QKV).
// MODE 1: bf16 partial out (split-K: kh ? C1 : C0), no bias.        (Wo)
// MODE 2: bf16 out + bias + relu.                                    (FFN1)
// MODE 3: bf16 partial out + bias only on kh==0.                     (FFN2)
template<int MODE>
__global__ __launch_bounds__(512, 2) void gemm8(
    const u16* __restrict__ A, const u16* __restrict__ Bt,
    void* __restrict__ C0, void* __restrict__ C1, const float* __restrict__ bias,
    int N, int KA, int nxt, int NT) {
  __shared__ u16 sA[2 * 16384];
  __shared__ u16 sB[2 * 16384];

  const int tid = threadIdx.x;
  const int lane = tid & 63;
  const int wid = tid >> 6;
  const int wm = wid >> 2, wn = wid & 3;
  const int l15 = lane & 15, l4 = lane >> 4;
  const int pk0 = l4 ^ (l15 & 7);

  // XCD swizzle: stripe of rpx row-tiles per XCD, COLUMN-major within stripe.
  // (chunk % gx == 0 for all launches: 64/16, 48/12, 32/8.)
  const int gx = gridDim.x;
  const int lin = blockIdx.y * gx + blockIdx.x;
  const int chunk = (gx * gridDim.y) >> 3;
  const int xcd = lin & 7;
  const int q = lin >> 3;
  const int rpx = chunk / gx;
  const int bym = xcd * rpx + (q % rpx);
  const int bxm = q / rpx;
  const int kh = (bxm >= nxt) ? 1 : 0;
  const int bm = bym * 256;
  const int bn = (bxm - kh * nxt) * 256;
  const int k0 = kh * NT * 64;

  const int srow = tid >> 3;
  const int gch = ((tid & 7) ^ (srow & 7)) * 8;
  const u16* Ag[4];
  const u16* Bg[4];
#pragma unroll
  for (int i = 0; i < 4; ++i) {
    Ag[i] = A + k0 + (size_t)(bm + i * 64 + srow) * KA + gch;
    Bg[i] = Bt + k0 + (size_t)(bn + i * 64 + srow) * KA + gch;
  }
  const int t8 = tid * 8;

#define ST1(tile, li)                                                              \
  do {                                                                             \
    if ((li) < 4) gload16(Ag[li] + (tile) * 64, sA + ((tile)&1) * 16384 + (li)*4096 + t8); \
    else gload16(Bg[(li)-4] + (tile) * 64, sB + ((tile)&1) * 16384 + ((li)-4) * 4096 + t8); \
  } while (0)
#define STG8(tile)                                         \
  if ((tile) < NT) {                                       \
    _Pragma("unroll") for (int li = 0; li < 8; ++li) ST1(tile, li); \
  }

  bf16v8 a[4][2], b[4][2];
  f32x4 acc[8][4];
#pragma unroll
  for (int m = 0; m < 8; ++m)
#pragma unroll
    for (int n = 0; n < 4; ++n) acc[m][n] = (f32x4){0.f, 0.f, 0.f, 0.f};

#define LDA(mh, buf)                                                        \
  {                                                                         \
    _Pragma("unroll") for (int mp = 0; mp < 4; ++mp) {                      \
      const u16* rp = (buf) + (size_t)(wm * 128 + (mh)*64 + mp * 16 + l15) * 64; \
      a[mp][0] = *(const bf16v8*)(rp + pk0 * 8);                            \
      a[mp][1] = *(const bf16v8*)(rp + (pk0 ^ 4) * 8);                      \
    }                                                                       \
  }
#define LDB(n0, buf)                                                        \
  {                                                                         \
    _Pragma("unroll") for (int nn = (n0); nn < (n0) + 2; ++nn) {            \
      const u16* rp = (buf) + (size_t)(wn * 64 + nn * 16 + l15) * 64;       \
      b[nn][0] = *(const bf16v8*)(rp + pk0 * 8);                            \
      b[nn][1] = *(const bf16v8*)(rp + (pk0 ^ 4) * 8);                      \
    }                                                                       \
  }
#define MMPH(mh, n0)                                                                      \
  {                                                                                       \
    __builtin_amdgcn_s_setprio(1);                                                        \
    _Pragma("unroll") for (int mp = 0; mp < 4; ++mp) {                                    \
      _Pragma("unroll") for (int nn = (n0); nn < (n0) + 2; ++nn) {                        \
        acc[(mh)*4 + mp][nn] = __builtin_amdgcn_mfma_f32_16x16x32_bf16(                   \
            a[mp][0], b[nn][0], acc[(mh)*4 + mp][nn], 0, 0, 0);                           \
        acc[(mh)*4 + mp][nn] = __builtin_amdgcn_mfma_f32_16x16x32_bf16(                   \
            a[mp][1], b[nn][1], acc[(mh)*4 + mp][nn], 0, 0, 0);                           \
      }                                                                                   \
    }                                                                                     \
    __builtin_amdgcn_s_setprio(0);                                                        \
  }

  // ---- prologue: tiles 0 and 1 fully staged; validate tile 0; pre-read frags ----
  STG8(0);
  STG8(1);
  __builtin_amdgcn_sched_barrier(0);
  asm volatile("s_waitcnt vmcnt(8)" ::: "memory");
  __builtin_amdgcn_s_barrier();
  LDA(0, sA);
  LDB(0, sB);

  for (int t = 0; t < NT; ++t) {
    u16* sAc = sA + (t & 1) * 16384;
    u16* sBc = sB + (t & 1) * 16384;
    u16* sAn = sA + ((t + 1) & 1) * 16384;
    u16* sBn = sB + ((t + 1) & 1) * 16384;
    // ---- p0 ----
    MMPH(0, 0);
    LDB(2, sBc);
    __builtin_amdgcn_s_barrier();
    // ---- p1 ---- (tile t buffer fully consumed after this phase)
    MMPH(0, 2);
    LDA(1, sAc);
    __builtin_amdgcn_s_barrier();
    // ---- p2: issue ALL of tile t+2 into buffer[t&1]; validate tile t+1 ----
    STG8(t + 2);
    MMPH(1, 0);
    __builtin_amdgcn_sched_barrier(0);
    if (t + 2 < NT)      asm volatile("s_waitcnt vmcnt(8)" ::: "memory");
    else if (t + 1 < NT) asm volatile("s_waitcnt vmcnt(0)" ::: "memory");
    __builtin_amdgcn_s_barrier();
    // ---- p3 ----
    MMPH(1, 2);
    if (t + 1 < NT) {
      LDA(0, sAn);
      LDB(0, sBn);
    }
    __builtin_amdgcn_s_barrier();
  }

  // ---- epilogue (R9-verified) ----
  const int lrow0 = bm + wm * 128 + l4 * 4;
  const int lcol0 = bn + wn * 64 + l15;
  const float scl = (MODE == 0 && ((bn >> 10) == 1)) ? QK_SCALE : 1.f;
  u16* Cw = (u16*)(kh ? C1 : C0);
#pragma unroll
  for (int m = 0; m < 8; ++m) {
#pragma unroll
    for (int n = 0; n < 4; ++n) {
      const int col = lcol0 + n * 16;
      float bv = 0.f;
      if (MODE == 2) bv = bias[col];
      if (MODE == 3) bv = kh ? 0.f : bias[col];
#pragma unroll
      for (int i = 0; i < 4; ++i) {
        const int row = lrow0 + m * 16 + i;
        float v = acc[m][n][i] + bv;
        if (MODE == 2) v = fmaxf(v, 0.f);
        if (MODE == 0) v *= scl;
        Cw[(size_t)row * N + col] = f2b(v);
      }
    }
  }
#undef ST1
#undef STG8
#undef LDA
#undef LDB
#undef MMPH
}

// ---------------- Flash attention: 8 waves x 32 q, 32x32 MFMA, swapped ops ----------------
// R9-verified source, exact (exp2f libm; permlane/builtin-exp2 permanently dropped).
#define MKPF(dst, A0, B0, C0, D0)                                             \
  {                                                                           \
    u32 sa = (u32)__shfl_xor((int)(A0), 32), sb = (u32)__shfl_xor((int)(B0), 32); \
    u32 sc = (u32)__shfl_xor((int)(C0), 32), sd = (u32)__shfl_xor((int)(D0), 32); \
    union { u32 u[4]; bf16v8 v; } cc;                                         \
    cc.u[0] = hi ? sc : (A0); cc.u[1] = hi ? sd : (B0);                       \
    cc.u[2] = hi ? (C0) : sa; cc.u[3] = hi ? (D0) : sb;                       \
    dst = cc.v;                                                               \
  }

__device__ __forceinline__ void vt_write64(u16* sVtBuf, int4 wv, int vr, int s8) {
  int4 w2;
  w2.x = __shfl_xor(wv.x, 8); w2.y = __shfl_xor(wv.y, 8);
  w2.z = __shfl_xor(wv.z, 8); w2.w = __shfl_xor(wv.w, 8);
  const int t = vr >> 1;
  const int odd = vr & 1;
  const u16* own = (const u16*)&wv;
  const u16* par = (const u16*)&w2;
  char* dstbase = (char*)sVtBuf + (t >> 2) * 1024 + (t & 3) * 4;
#pragma unroll
  for (int k = 0; k < 4; k++) {
    const unsigned lo = odd ? (unsigned)par[4 + k] : (unsigned)own[k];
    const unsigned h2 = odd ? (unsigned)own[4 + k] : (unsigned)par[k];
    const int d = s8 * 8 + k + (odd ? 4 : 0);
    const int dsw = d ^ s8;  // s8 == d>>3
    *(unsigned*)(dstbase + dsw * 16) = lo | (h2 << 16);
  }
}

__global__ __launch_bounds__(512, 4) void attn_fa(
    const u16* __restrict__ qkv, u16* __restrict__ attn) {
  __shared__ u16 sK[2][64 * 64];
  __shared__ u16 sVt[2][64 * 64];

  const int tid = threadIdx.x, lane = tid & 63;
  const int l31 = lane & 31, hi = lane >> 5;
  const int w = ((blockIdx.x & 7) << 6) + (blockIdx.x >> 3);  // XCD swizzle (512 blocks)
  const int bh = w >> 2;
  const int b = bh >> 4, h = bh & 15;
  const int qrow0 = (w & 3) * 256 + (tid >> 6) * 32;
  const size_t rowb = (size_t)b * S_LEN * QKV_LD;
  const u16* kg = qkv + rowb + h * HD_DIM;
  const u16* qg = qkv + rowb + 1024 + h * HD_DIM;
  const u16* vg = qkv + rowb + 2048 + h * HD_DIM;
  const size_t obase = (size_t)b * (S_LEN * E_DIM) + (size_t)h * HD_DIM;

  bf16v8 qf[4];
#pragma unroll
  for (int ks = 0; ks < 4; ++ks)
    qf[ks] = *(const bf16v8*)(qg + (size_t)(qrow0 + l31) * QKV_LD + ks * 16 + hi * 8);

  const int kr = tid >> 3;
  const int s8 = tid & 7;
  const u16* kgsrc = kg + (size_t)kr * QKV_LD + ((s8 ^ (kr & 7)) * 8);
  const u16* vgsrc = vg + (size_t)kr * QKV_LD + s8 * 8;

  f32x16 accT[2];
#pragma unroll
  for (int i = 0; i < 16; ++i) { accT[0][i] = 0.f; accT[1][i] = 0.f; }
  float mrun = -1e30f, lrun = 0.f;

  gload16(kgsrc, sK[0] + tid * 8);
  {
    int4 v0 = *(const int4*)(vgsrc);
    vt_write64(sVt[0], v0, kr, s8);
  }
  __syncthreads();

  for (int t = 0; t < 16; ++t) {
    const int cur = t & 1;
    int4 vreg;
    if (t < 15) {
      gload16(kgsrc + (size_t)(t + 1) * 64 * QKV_LD, sK[cur ^ 1] + tid * 8);
      vreg = *(const int4*)(vgsrc + (size_t)(t + 1) * 64 * QKV_LD);
    }

    f32x16 T0, T1;
#pragma unroll
    for (int i = 0; i < 16; ++i) { T0[i] = 0.f; T1[i] = 0.f; }
#pragma unroll
    for (int ks = 0; ks < 4; ++ks) {
      const int ch = ((2 * ks + hi) ^ (l31 & 7)) * 8;
      const bf16v8 k0 = *(const bf16v8*)(sK[cur] + (size_t)l31 * 64 + ch);
      const bf16v8 k1 = *(const bf16v8*)(sK[cur] + (size_t)(32 + l31) * 64 + ch);
      T0 = __builtin_amdgcn_mfma_f32_32x32x16_bf16(k0, qf[ks], T0, 0, 0, 0);
      T1 = __builtin_amdgcn_mfma_f32_32x32x16_bf16(k1, qf[ks], T1, 0, 0, 0);
    }

    // ---- online softmax: max3 tree + single cross-half shfl ----
    float ma = fmaxf(T0[0], T0[1]);
#pragma unroll
    for (int r = 2; r < 16; r += 2) ma = max3f(ma, T0[r], T0[r + 1]);
    float mb = fmaxf(T1[0], T1[1]);
#pragma unroll
    for (int r = 2; r < 16; r += 2) mb = max3f(mb, T1[r], T1[r + 1]);
    float mx = fmaxf(ma, mb);
    mx = fmaxf(mx, __shfl_xor(mx, 32));
    const bool skip = __all(mx <= mrun + 8.f);
    const float mnew = skip ? mrun : fmaxf(mrun, mx);
    float rs = 0.f;
#pragma unroll
    for (int r = 0; r < 16; ++r) { T0[r] = exp2f(T0[r] - mnew); rs += T0[r]; }
#pragma unroll
    for (int r = 0; r < 16; ++r) { T1[r] = exp2f(T1[r] - mnew); rs += T1[r]; }
    // lrun stays lane-local (esc uniform across the lane pair); merged in epilogue
    if (skip) {
      lrun += rs;
    } else {
      const float esc = exp2f(mrun - mnew);
      mrun = mnew;
      lrun = lrun * esc + rs;
#pragma unroll
      for (int r = 0; r < 16; ++r) { accT[0][r] *= esc; accT[1][r] *= esc; }
    }

    u32 P0[8], P1[8];
#pragma unroll
    for (int wd = 0; wd < 8; ++wd) {
      asm("v_cvt_pk_bf16_f32 %0, %1, %2" : "=v"(P0[wd]) : "v"(T0[2 * wd]), "v"(T0[2 * wd + 1]));
      asm("v_cvt_pk_bf16_f32 %0, %1, %2" : "=v"(P1[wd]) : "v"(T1[2 * wd]), "v"(T1[2 * wd + 1]));
    }
    bf16v8 pf[4];
    MKPF(pf[0], P0[0], P0[1], P0[2], P0[3]);
    MKPF(pf[1], P0[4], P0[5], P0[6], P0[7]);
    MKPF(pf[2], P1[0], P1[1], P1[2], P1[3]);
    MKPF(pf[3], P1[4], P1[5], P1[6], P1[7]);

#pragma unroll
    for (int dblk = 0; dblk < 2; ++dblk) {
      const int dd = dblk * 32 + l31;
      const int drow = (dd ^ (dd >> 3)) * 8;
#pragma unroll
      for (int ks = 0; ks < 4; ++ks) {
        const bf16v8 va = *(const bf16v8*)(sVt[cur] + (2 * ks + hi) * 512 + drow);
        accT[dblk] = __builtin_amdgcn_mfma_f32_32x32x16_bf16(va, pf[ks], accT[dblk], 0, 0, 0);
      }
    }

    if (t < 15) vt_write64(sVt[cur ^ 1], vreg, kr, s8);
    __syncthreads();
  }

  // ---- epilogue: merge lane-local lrun across halves, normalize, store ----
  lrun += __shfl_xor(lrun, 32);
  const float linv = 1.f / lrun;
  u16* orow = attn + obase + (size_t)(qrow0 + l31) * E_DIM;
#pragma unroll
  for (int dblk = 0; dblk < 2; ++dblk)
#pragma unroll
    for (int a4 = 0; a4 < 4; ++a4) {
      ushort4 st;
      st.x = f2b(accT[dblk][4 * a4 + 0] * linv);
      st.y = f2b(accT[dblk][4 * a4 + 1] * linv);
      st.z = f2b(accT[dblk][4 * a4 + 2] * linv);
      st.w = f2b(accT[dblk][4 * a4 + 3] * linv);
      *(ushort4*)(orow + dblk * 32 + a4 * 8 + hi * 4) = st;
    }
}

// ---------------- LayerNorm over bf16 inputs (1 block = 1 row of 1024), ddof=1 ----
// MODE 0: y = 2*(a+b), bf16 out (ln1 over Wo split-K partials)
// MODE 1: y = a+b+c,  f32 out  (ln2 over x1 + FFN2 partials)
template<int MODE>
__global__ __launch_bounds__(256) void ln_b16(
    const u16* __restrict__ a, const u16* __restrict__ b, const u16* __restrict__ c,
    const float* __restrict__ scale, const float* __restrict__ bias,
    float* __restrict__ outf, u16* __restrict__ outb) {
  const int row = blockIdx.x;
  const int tid = threadIdx.x;
  const size_t off = (size_t)row * 1024 + tid * 4;
  ushort4 av = *(const ushort4*)(a + off);
  ushort4 bv = *(const ushort4*)(b + off);
  float4 v;
  v.x = b2f(av.x) + b2f(bv.x);
  v.y = b2f(av.y) + b2f(bv.y);
  v.z = b2f(av.z) + b2f(bv.z);
  v.w = b2f(av.w) + b2f(bv.w);
  if (MODE == 0) {
    v.x *= 2.f; v.y *= 2.f; v.z *= 2.f; v.w *= 2.f;
  } else {
    ushort4 cv = *(const ushort4*)(c + off);
    v.x += b2f(cv.x); v.y += b2f(cv.y); v.z += b2f(cv.z); v.w += b2f(cv.w);
  }
  float s = v.x + v.y + v.z + v.w;
  float q = v.x * v.x + v.y * v.y + v.z * v.z + v.w * v.w;
#pragma unroll
  for (int o = 1; o < 64; o <<= 1) { s += __shfl_xor(s, o); q += __shfl_xor(q, o); }
  __shared__ float red[8];
  const int wave = tid >> 6, lane = tid & 63;
  if (lane == 0) { red[wave] = s; red[4 + wave] = q; }
  __syncthreads();
  s = red[0] + red[1] + red[2] + red[3];
  q = red[4] + red[5] + red[6] + red[7];
  const float mean = s * (1.f / 1024.f);
  const float var = (q - 1024.f * mean * mean) * (1.f / 1023.f);
  const float rstd = rsqrtf(var + 1e-5f);
  const int cc = tid * 4;
  float4 sc = *(const float4*)(scale + cc);
  float4 bi = *(const float4*)(bias + cc);
  float4 o;
  o.x = sc.x * (v.x - mean) * rstd + bi.x;
  o.y = sc.y * (v.y - mean) * rstd + bi.y;
  o.z = sc.z * (v.z - mean) * rstd + bi.z;
  o.w = sc.w * (v.w - mean) * rstd + bi.w;
  if (MODE == 0) {
    ushort4 ob;
    ob.x = f2b(o.x); ob.y = f2b(o.y); ob.z = f2b(o.z); ob.w = f2b(o.w);
    *(ushort4*)(outb + off) = ob;
  } else {
    *(float4*)(outf + off) = o;
  }
}

// ---------------- fp32 -> bf16 cast (4 elems/thread) ----------------
__global__ __launch_bounds__(256) void cast_bf16_k(const float* __restrict__ in,
                                                   u16* __restrict__ out, int n4) {
  const int i = blockIdx.x * blockDim.x + threadIdx.x;
  if (i >= n4) return;
  float4 v = *(const float4*)(in + (size_t)i * 4);
  ushort4 o;
  o.x = f2b(v.x); o.y = f2b(v.y); o.z = f2b(v.z); o.w = f2b(v.w);
  *(ushort4*)(out + (size_t)i * 4) = o;
}

// ---------------- 1024x1024 fp32 transpose + bf16 cast ----------------
__global__ __launch_bounds__(256) void transpose_cast_k(const float* __restrict__ in,
                                                        u16* __restrict__ out) {
  __shared__ float tile[32][33];
  const int tx = threadIdx.x & 31, ty = threadIdx.x >> 5;
  const int bx = blockIdx.x * 32, by = blockIdx.y * 32;
#pragma unroll
  for (int j = 0; j < 4; j++)
    tile[ty + j * 8][tx] = in[(size_t)(by + ty + j * 8) * 1024 + bx + tx];
  __syncthreads();
#pragma unroll
  for (int j = 0; j < 4; j++)
    out[(size_t)(bx + ty + j * 8) * 1024 + by + tx] = f2b(tile[tx][ty + j * 8]);
}

extern "C" void kernel_launch(void* const* d_in, const int* in_sizes, int n_in,
                              void* d_out, int out_size, void* d_ws, size_t ws_size,
                              hipStream_t stream) {
  const float* x    = (const float*)d_in[0];
  const float* in_w = (const float*)d_in[1];
  const float* out_w = (const float*)d_in[2];
  const float* ln1s = (const float*)d_in[3];
  const float* ln1b = (const float*)d_in[4];
  const float* ln2s = (const float*)d_in[5];
  const float* ln2b = (const float*)d_in[6];
  const float* w1   = (const float*)d_in[7];
  const float* b1   = (const float*)d_in[8];
  const float* w2   = (const float*)d_in[9];
  const float* b2   = (const float*)d_in[10];
  float* outp = (float*)d_out;

  char* ws = (char*)d_ws;
  // arena (peak 176,160,768 B):
  u16*   xb    = (u16*)(ws + 0);            // 16.8M; dead after QKV gemm
  u16*   qkv   = (u16*)(ws + 16777216);     // 50.3M; dead after attn
  u16*   attnb = (u16*)(ws + 0);            // 16.8M over dead xb; dead after Wo
  u16*   wo0   = (u16*)(ws + 67108864);     // 16.8M bf16 partial; dead after ln1
  u16*   wo1   = (u16*)(ws + 83886080);     // 16.8M bf16 partial; dead after ln1
  u16*   x1b   = (u16*)(ws + 100663296);    // 16.8M; read by FFN1 and ln2
  u16*   Hb    = (u16*)(ws + 0);            // 67.1M over dead xb/qkv/attnb
  u16*   ffn0b = (u16*)(ws + 67108864);     // 16.8M over dead wo0
  u16*   ffn1b = (u16*)(ws + 83886080);     // 16.8M over dead wo1
  u16*   wkt   = (u16*)(ws + 150994944);    // [3072][1024] concat k,q,v transposed
  u16*   wot   = wkt + 3145728;
  u16*   w1b   = wot + 1048576;
  u16*   w2b   = w1b + 4194304;
  (void)ws_size; (void)in_sizes; (void)n_in; (void)out_size;

  // casts / transposes
  cast_bf16_k<<<8192, 256, 0, stream>>>(x, xb, 2097152);
  cast_bf16_k<<<4096, 256, 0, stream>>>(w1, w1b, 1048576);
  cast_bf16_k<<<4096, 256, 0, stream>>>(w2, w2b, 1048576);
  dim3 tg(32, 32);
  transpose_cast_k<<<tg, 256, 0, stream>>>(in_w + 0,       wkt);            // k
  transpose_cast_k<<<tg, 256, 0, stream>>>(in_w + 1048576, wkt + 1048576); // q
  transpose_cast_k<<<tg, 256, 0, stream>>>(in_w + 2097152, wkt + 2097152); // v
  transpose_cast_k<<<tg, 256, 0, stream>>>(out_w,          wot);

  // fused QKV projection: [8192][3072], q block scaled by QK_SCALE
  gemm8<0><<<dim3(12, 32), 512, 0, stream>>>(xb, wkt, qkv, nullptr, nullptr, 3072, 1024, 12, 16);

  // attention: 512 blocks x 512 threads (256 q rows per block)
  attn_fa<<<512, 512, 0, stream>>>(qkv, attnb);

  // output projection, split-K=2 -> two bf16 partials
  gemm8<1><<<dim3(8, 32), 512, 0, stream>>>(attnb, wot, wo0, wo1, nullptr, 1024, 1024, 4, 8);

  // ln1: x1 = LN(2*(wo0+wo1)) -> bf16
  ln_b16<0><<<8192, 256, 0, stream>>>(wo0, wo1, nullptr, ln1s, ln1b, nullptr, x1b);

  // FFN1: bf16 + bias + relu
  gemm8<2><<<dim3(16, 32), 512, 0, stream>>>(x1b, w1b, Hb, nullptr, b1, 4096, 1024, 16, 16);

  // FFN2: split-K=2, bf16 partials (bias on partial 0)
  gemm8<3><<<dim3(8, 32), 512, 0, stream>>>(Hb, w2b, ffn0b, ffn1b, b2, 1024, 4096, 4, 32);

  // ln2: out = LN(x1 + ffn0 + ffn1) -> f32
  ln_b16<1><<<8192, 256, 0, stream>>>(x1b, ffn0b, ffn1b, ln2s, ln2b, outp, nullptr);
}